// Round 12
// baseline (209.659 us; speedup 1.0000x reference)
//
#include <hip/hip_runtime.h>
#include <hip/hip_bf16.h>
#include <math.h>

// DualTimeConstantAdaptation: y = full cross-correlation(softplus(x), kern),
// kern[k] = (a1^k + a2^k)/S, K=4800.
// Infinite-scan difference form: G_c(s) = a_c*G_c(s+1) + w[s] (reverse scan),
//   y[t] = (G1(s) + G2(s) - c2*G2(s+K)) / S,  s = t-(K-1), c2 = a2^K.
// Zero-init ghosts cancel EXACTLY -> no halo truncation error. G2(s+K) via a
// 5-tile-deep per-lane register ring (K = 5 tiles of 960), packed bf16.
// R10: latency-bound at 12% occupancy -> 11 segments/channel (wave-serial
// chain 16->10 tiles), 4 independent wave-segments per 256-thread block
// (2560 -> 5632 waves).

#define TT    48000
#define KK    4800
#define OUTT  52799
#define SEGS  11                 // wave-segments per channel
#define E     15                 // elements per lane
#define TILE  960                // 64 lanes * E
#define NSTT  5                  // store tiles per segment
#define LSEG  (NSTT * TILE)      // 4800 stored positions per segment
#define NT    10                 // traversal tiles = NSTT + KK/TILE
#define RD    5                  // ring depth = KK/TILE
#define SMIN  (TT - SEGS * LSEG) // -4800

__device__ __forceinline__ float softplus_fast(float v) {
    // log(1+e^v) via v_exp/v_log; input is randn (|v| < ~6) -> no overflow
    return __logf(1.0f + __expf(v));
}

__device__ __forceinline__ unsigned pack_bf2(float a, float b) {
    union { __hip_bfloat16 h; unsigned short u; } ca, cb;
    ca.h = __float2bfloat16(a);
    cb.h = __float2bfloat16(b);
    return (unsigned)ca.u | ((unsigned)cb.u << 16);
}

__device__ __forceinline__ float2 unpack_bf2(unsigned v) {
    union { unsigned u; float f; } fa, fb;
    fa.u = (v & 0xffffu) << 16;
    fb.u = v & 0xffff0000u;
    return make_float2(fa.f, fb.f);
}

template <int SLOT, bool STORES>
__device__ __forceinline__ void tile_step(
    int tau, int segTop, int lane,
    const float* __restrict__ xc, float* __restrict__ yc,
    float a1, float a2, float c2, float invS,
    const float (&p1)[E + 1], const float (&p2)[E + 1],
    float P1, float P2,
    float& pc1, float& pc2,
    unsigned (&ring)[RD][8])
{
    const int sLow = segTop - (tau + 1) * TILE;
    const int s0 = sLow + E * lane;

    // load softplus(x[s0..s0+14]), zero outside [0,TT)
    float xs[E];
    if (s0 >= 0 && s0 + E <= TT) {
        #pragma unroll
        for (int j = 0; j < E; ++j) xs[j] = softplus_fast(xc[s0 + j]);
    } else {
        #pragma unroll
        for (int j = 0; j < E; ++j) {
            const int ss = s0 + j;
            xs[j] = (ss >= 0 && ss < TT) ? softplus_fast(xc[ss]) : 0.0f;
        }
    }

    // local zero-init suffix scans over the lane's E positions
    float L1[E], L2[E];
    float h1 = 0.0f, h2 = 0.0f;
    #pragma unroll
    for (int j = E - 1; j >= 0; --j) {
        h1 = fmaf(a1, h1, xs[j]); L1[j] = h1;
        h2 = fmaf(a2, h2, xs[j]); L2[j] = h2;
    }

    // wave-level suffix scan of lane aggregates (decay A_c = a_c^E = p[E])
    float sc1 = L1[0], sc2 = L2[0];
    float f1 = p1[E], f2 = p2[E];
    #pragma unroll
    for (int d = 1; d < 64; d <<= 1) {
        float v1 = __shfl_down(sc1, d);
        float v2 = __shfl_down(sc2, d);
        if (lane + d >= 64) { v1 = 0.0f; v2 = 0.0f; }
        sc1 = fmaf(f1, v1, sc1);
        sc2 = fmaf(f2, v2, sc2);
        f1 *= f1; f2 *= f2;
    }
    // G at this lane's lowest position (carry folded via P = a^(TILE - E*lane))
    const float S1 = fmaf(P1, pc1, sc1);
    const float S2 = fmaf(P2, pc2, sc2);
    // carry INTO this lane = G at s0+E (lane+1's S; lane 63 <- tile carry)
    float cin1 = __shfl_down(S1, 1);
    float cin2 = __shfl_down(S2, 1);
    if (lane == 63) { cin1 = pc1; cin2 = pc2; }
    // carry for the next (lower) tile = G at sLow (lane 0's S)
    pc1 = __shfl(S1, 0);
    pc2 = __shfl(S2, 0);

    // per-element slow-chain values G2(s0+j)
    float g2v[16];
    #pragma unroll
    for (int j = 0; j < E; ++j) g2v[j] = fmaf(p2[E - j], cin2, L2[j]);
    g2v[15] = 0.0f;

    if (STORES) {
        // ring slot currently holds G2 of tile tau-RD (positions s0+KK)
        float old[16];
        #pragma unroll
        for (int p = 0; p < 8; ++p) {
            const float2 f = unpack_bf2(ring[SLOT][p]);
            old[2 * p] = f.x; old[2 * p + 1] = f.y;
        }
        const int t0 = s0 + (KK - 1);
        float out[E];
        #pragma unroll
        for (int j = 0; j < E; ++j) {
            const float g1 = fmaf(p1[E - j], cin1, L1[j]);
            out[j] = (g1 + g2v[j] - c2 * old[j]) * invS;
        }
        if (t0 >= 0) {
            #pragma unroll
            for (int j = 0; j < E; ++j) yc[t0 + j] = out[j];
        } else {
            #pragma unroll
            for (int j = 0; j < E; ++j) if (t0 + j >= 0) yc[t0 + j] = out[j];
        }
    }

    // overwrite slot with current tile's G2 (consumed at tau+RD)
    #pragma unroll
    for (int p = 0; p < 8; ++p)
        ring[SLOT][p] = pack_bf2(g2v[2 * p], g2v[2 * p + 1]);
}

__global__ __launch_bounds__(256) void dtca_ring_kernel(
    const float* __restrict__ x, float* __restrict__ y,
    float a1, float a2, float c2, float invS, int nch)
{
    const int wid  = blockIdx.x * 4 + (threadIdx.x >> 6);  // global wave-segment id
    const int lane = threadIdx.x & 63;
    const int ch   = wid / SEGS;
    const int seg  = wid - ch * SEGS;
    if (ch >= nch) return;

    const float* __restrict__ xc = x + (size_t)ch * TT;
    float* __restrict__ yc       = y + (size_t)ch * OUTT;

    const int segLo  = SMIN + seg * LSEG;
    const int segTop = segLo + NT * TILE;

    float p1[E + 1], p2[E + 1];
    p1[0] = 1.0f; p2[0] = 1.0f;
    #pragma unroll
    for (int k = 1; k <= E; ++k) { p1[k] = p1[k - 1] * a1; p2[k] = p2[k - 1] * a2; }
    const float P1 = __powf(a1, (float)(TILE - E * lane));
    const float P2 = __powf(a2, (float)(TILE - E * lane));

    unsigned ring[RD][8];
    #pragma unroll
    for (int r = 0; r < RD; ++r)
        #pragma unroll
        for (int p = 0; p < 8; ++p) ring[r][p] = 0u;

    float pc1 = 0.0f, pc2 = 0.0f;

    #define TSTEP(SL, ST, TAU) \
        tile_step<SL, ST>(TAU, segTop, lane, xc, yc, a1, a2, c2, invS, \
                          p1, p2, P1, P2, pc1, pc2, ring)

    // warm-up tiles: cover [segLo+LSEG, segTop) = K positions, no stores
    TSTEP(0, false, 0);
    TSTEP(1, false, 1);
    TSTEP(2, false, 2);
    TSTEP(3, false, 3);
    TSTEP(4, false, 4);
    // store tiles: cover [segLo, segLo+LSEG)
    TSTEP(0, true, 5);
    TSTEP(1, true, 6);
    TSTEP(2, true, 7);
    TSTEP(3, true, 8);
    TSTEP(4, true, 9);
    #undef TSTEP
}

extern "C" void kernel_launch(void* const* d_in, const int* in_sizes, int n_in,
                              void* d_out, int out_size, void* d_ws, size_t ws_size,
                              hipStream_t stream) {
    const float* x = (const float*)d_in[0];
    float* y = (float*)d_out;

    const int nelem = in_sizes[0];
    const int nch   = nelem / TT;      // B*C = 512

    const double a1d = exp(-1.0 / 32.0);
    const double a2d = exp(-1.0 / 960.0);
    const double c1d = exp(-4800.0 / 32.0);   // ~7e-66 -> 0 in fp32
    const double c2d = exp(-4800.0 / 960.0);  // e^-5
    const double S   = (1.0 - c1d) / (1.0 - a1d) + (1.0 - c2d) / (1.0 - a2d);

    const int nwaveseg = nch * SEGS;                 // 5632
    const int blocks   = (nwaveseg + 3) / 4;         // 1408
    dtca_ring_kernel<<<blocks, 256, 0, stream>>>(
        x, y, (float)a1d, (float)a2d, (float)c2d, (float)(1.0 / S), nch);
}

// Round 16
// 205.620 us; speedup vs baseline: 1.0196x; 1.0196x over previous
//
#include <hip/hip_runtime.h>
#include <hip/hip_bf16.h>
#include <math.h>

// DualTimeConstantAdaptation: y = full cross-correlation(softplus(x), kern),
// kern[k] = (a1^k + a2^k)/S, K=4800.
// Infinite-scan difference form: G_c(s) = a_c*G_c(s+1) + w[s] (reverse scan),
//   y[t] = (G1(s) + G2(s) - c2*G2(s+K)) / S,  s = t-(K-1), c2 = a2^K.
// Ghosts cancel exactly; G2(s+K) via 5-deep bf16 register ring.
// R12: latency-bound inside the wave (loads issued after dependent compute)
// -> double-buffered issue-early prefetch: tile tau+1's raw loads fly during
// tile tau's compute. Geometry unchanged from R10 (SEGS=11, 4 waves/block).

#define TT    48000
#define KK    4800
#define OUTT  52799
#define SEGS  11                 // wave-segments per channel
#define E     15                 // elements per lane
#define TILE  960                // 64 lanes * E
#define NSTT  5                  // store tiles per segment
#define LSEG  (NSTT * TILE)      // 4800 stored positions per segment
#define NT    10                 // traversal tiles = NSTT + KK/TILE
#define RD    5                  // ring depth = KK/TILE
#define SMIN  (TT - SEGS * LSEG) // -4800
#define NEGPAD (-1.0e30f)        // softplus(NEGPAD) == 0 exactly

__device__ __forceinline__ float softplus_fast(float v) {
    // log(1+e^v) via v_exp/v_log; randn input -> no overflow; exp(-1e30)=0
    return __logf(1.0f + __expf(v));
}

__device__ __forceinline__ unsigned pack_bf2(float a, float b) {
    union { __hip_bfloat16 h; unsigned short u; } ca, cb;
    ca.h = __float2bfloat16(a);
    cb.h = __float2bfloat16(b);
    return (unsigned)ca.u | ((unsigned)cb.u << 16);
}

__device__ __forceinline__ float2 unpack_bf2(unsigned v) {
    union { unsigned u; float f; } fa, fb;
    fa.u = (v & 0xffffu) << 16;
    fb.u = v & 0xffff0000u;
    return make_float2(fa.f, fb.f);
}

// raw loads of x[s0..s0+14]; OOB slots get NEGPAD (softplus -> 0)
__device__ __forceinline__ void ld_raw(float (&o)[E], const float* __restrict__ xc, int s0) {
    if (s0 >= 0 && s0 + E <= TT) {
        #pragma unroll
        for (int j = 0; j < E; ++j) o[j] = xc[s0 + j];
    } else {
        #pragma unroll
        for (int j = 0; j < E; ++j) {
            const int ss = s0 + j;
            o[j] = (ss >= 0 && ss < TT) ? xc[ss] : NEGPAD;
        }
    }
}

template <int SLOT, bool STORES, bool PREF>
__device__ __forceinline__ void tile_step(
    int tau, int segTop, int lane,
    const float* __restrict__ xc, float* __restrict__ yc,
    float a1, float a2, float c2, float invS,
    const float (&p1)[E + 1], const float (&p2)[E + 1],
    float P1, float P2,
    float& pc1, float& pc2,
    unsigned (&ring)[RD][8],
    float (&cur)[E], float (&nxt)[E])
{
    const int sLow = segTop - (tau + 1) * TILE;
    const int s0 = sLow + E * lane;

    // ISSUE-EARLY: next tile's loads fly during this tile's compute
    if (PREF) ld_raw(nxt, xc, s0 - TILE);

    float xs[E];
    #pragma unroll
    for (int j = 0; j < E; ++j) xs[j] = softplus_fast(cur[j]);

    // local zero-init suffix scans over the lane's E positions
    float L1[E], L2[E];
    float h1 = 0.0f, h2 = 0.0f;
    #pragma unroll
    for (int j = E - 1; j >= 0; --j) {
        h1 = fmaf(a1, h1, xs[j]); L1[j] = h1;
        h2 = fmaf(a2, h2, xs[j]); L2[j] = h2;
    }

    // wave-level suffix scan of lane aggregates (decay A_c = a_c^E = p[E])
    float sc1 = L1[0], sc2 = L2[0];
    float f1 = p1[E], f2 = p2[E];
    #pragma unroll
    for (int d = 1; d < 64; d <<= 1) {
        float v1 = __shfl_down(sc1, d);
        float v2 = __shfl_down(sc2, d);
        if (lane + d >= 64) { v1 = 0.0f; v2 = 0.0f; }
        sc1 = fmaf(f1, v1, sc1);
        sc2 = fmaf(f2, v2, sc2);
        f1 *= f1; f2 *= f2;
    }
    // G at this lane's lowest position (carry folded via P = a^(TILE - E*lane))
    const float S1 = fmaf(P1, pc1, sc1);
    const float S2 = fmaf(P2, pc2, sc2);
    // carry INTO this lane = G at s0+E (lane+1's S; lane 63 <- tile carry)
    float cin1 = __shfl_down(S1, 1);
    float cin2 = __shfl_down(S2, 1);
    if (lane == 63) { cin1 = pc1; cin2 = pc2; }
    // carry for the next (lower) tile = G at sLow (lane 0's S)
    pc1 = __shfl(S1, 0);
    pc2 = __shfl(S2, 0);

    // per-element slow-chain values G2(s0+j)
    float g2v[16];
    #pragma unroll
    for (int j = 0; j < E; ++j) g2v[j] = fmaf(p2[E - j], cin2, L2[j]);
    g2v[15] = 0.0f;

    if (STORES) {
        // ring slot currently holds G2 of tile tau-RD (positions s0+KK)
        float old[16];
        #pragma unroll
        for (int p = 0; p < 8; ++p) {
            const float2 f = unpack_bf2(ring[SLOT][p]);
            old[2 * p] = f.x; old[2 * p + 1] = f.y;
        }
        const int t0 = s0 + (KK - 1);
        float out[E];
        #pragma unroll
        for (int j = 0; j < E; ++j) {
            const float g1 = fmaf(p1[E - j], cin1, L1[j]);
            out[j] = (g1 + g2v[j] - c2 * old[j]) * invS;
        }
        if (t0 >= 0) {
            #pragma unroll
            for (int j = 0; j < E; ++j) yc[t0 + j] = out[j];
        } else {
            #pragma unroll
            for (int j = 0; j < E; ++j) if (t0 + j >= 0) yc[t0 + j] = out[j];
        }
    }

    // overwrite slot with current tile's G2 (consumed at tau+RD)
    #pragma unroll
    for (int p = 0; p < 8; ++p)
        ring[SLOT][p] = pack_bf2(g2v[2 * p], g2v[2 * p + 1]);
}

__global__ __launch_bounds__(256) void dtca_ring_kernel(
    const float* __restrict__ x, float* __restrict__ y,
    float a1, float a2, float c2, float invS, int nch)
{
    const int wid  = blockIdx.x * 4 + (threadIdx.x >> 6);  // global wave-segment id
    const int lane = threadIdx.x & 63;
    const int ch   = wid / SEGS;
    const int seg  = wid - ch * SEGS;
    if (ch >= nch) return;

    const float* __restrict__ xc = x + (size_t)ch * TT;
    float* __restrict__ yc       = y + (size_t)ch * OUTT;

    const int segLo  = SMIN + seg * LSEG;
    const int segTop = segLo + NT * TILE;

    float p1[E + 1], p2[E + 1];
    p1[0] = 1.0f; p2[0] = 1.0f;
    #pragma unroll
    for (int k = 1; k <= E; ++k) { p1[k] = p1[k - 1] * a1; p2[k] = p2[k - 1] * a2; }
    const float P1 = __powf(a1, (float)(TILE - E * lane));
    const float P2 = __powf(a2, (float)(TILE - E * lane));

    unsigned ring[RD][8];
    #pragma unroll
    for (int r = 0; r < RD; ++r)
        #pragma unroll
        for (int p = 0; p < 8; ++p) ring[r][p] = 0u;

    float pc1 = 0.0f, pc2 = 0.0f;
    float bufA[E], bufB[E];

    #define TSTEP(SL, ST, PF, TAU, CUR, NXT) \
        tile_step<SL, ST, PF>(TAU, segTop, lane, xc, yc, a1, a2, c2, invS, \
                              p1, p2, P1, P2, pc1, pc2, ring, CUR, NXT)

    // preload tile 0
    ld_raw(bufA, xc, segTop - TILE + E * lane);

    // warm-up tiles: cover [segLo+LSEG, segTop) = K positions, no stores
    TSTEP(0, false, true, 0, bufA, bufB);
    TSTEP(1, false, true, 1, bufB, bufA);
    TSTEP(2, false, true, 2, bufA, bufB);
    TSTEP(3, false, true, 3, bufB, bufA);
    TSTEP(4, false, true, 4, bufA, bufB);
    // store tiles: cover [segLo, segLo+LSEG)
    TSTEP(0, true, true, 5, bufB, bufA);
    TSTEP(1, true, true, 6, bufA, bufB);
    TSTEP(2, true, true, 7, bufB, bufA);
    TSTEP(3, true, true, 8, bufA, bufB);
    TSTEP(4, true, false, 9, bufB, bufA);
    #undef TSTEP
}

extern "C" void kernel_launch(void* const* d_in, const int* in_sizes, int n_in,
                              void* d_out, int out_size, void* d_ws, size_t ws_size,
                              hipStream_t stream) {
    const float* x = (const float*)d_in[0];
    float* y = (float*)d_out;

    const int nelem = in_sizes[0];
    const int nch   = nelem / TT;      // B*C = 512

    const double a1d = exp(-1.0 / 32.0);
    const double a2d = exp(-1.0 / 960.0);
    const double c1d = exp(-4800.0 / 32.0);   // ~7e-66 -> 0 in fp32
    const double c2d = exp(-4800.0 / 960.0);  // e^-5
    const double S   = (1.0 - c1d) / (1.0 - a1d) + (1.0 - c2d) / (1.0 - a2d);

    const int nwaveseg = nch * SEGS;                 // 5632
    const int blocks   = (nwaveseg + 3) / 4;         // 1408
    dtca_ring_kernel<<<blocks, 256, 0, stream>>>(
        x, y, (float)a1d, (float)a2d, (float)c2d, (float)(1.0 / S), nch);
}